// Round 1
// baseline (526.908 us; speedup 1.0000x reference)
//
#include <hip/hip_runtime.h>
#include <cmath>
#include <cstdint>

// Shapes (fixed for this problem)
#define BB 4
#define SS 2048
#define EE 1024
#define HH 16
#define DD 64
#define ROWS (BB*SS)          // 8192
#define QKV_N (3*EE)          // 3072

using bf16x8 = __attribute__((ext_vector_type(8))) __bf16;
using bf16x4 = __attribute__((ext_vector_type(4))) __bf16;
using f32x4  = __attribute__((ext_vector_type(4))) float;

__device__ inline f32x4 mfma16(bf16x8 a, bf16x8 b, f32x4 c) {
    return __builtin_amdgcn_mfma_f32_16x16x32_bf16(a, b, c, 0, 0, 0);
}

__device__ inline void load_lds16(const void* g, void* l) {
    __builtin_amdgcn_global_load_lds(
        (__attribute__((address_space(1))) void*)g,
        (__attribute__((address_space(3))) void*)l, 16, 0, 0);
}

// ---------------- cast fp32 -> bf16, vectorized ----------------
__global__ __launch_bounds__(256) void cast_f32_bf16(const float* __restrict__ in,
                                                     __bf16* __restrict__ out) {
    size_t i = ((size_t)blockIdx.x * 256 + threadIdx.x) * 4;
    float4 v = *(const float4*)(in + i);
    bf16x4 o;
    o[0] = (__bf16)v.x; o[1] = (__bf16)v.y; o[2] = (__bf16)v.z; o[3] = (__bf16)v.w;
    *(bf16x4*)(out + i) = o;
}

// ---------------- transpose + cast: in [K][N] f32 -> out [N][K] bf16 ----------------
__global__ __launch_bounds__(256) void transpose_cast(const float* __restrict__ in,
                                                      __bf16* __restrict__ out,
                                                      int K, int N) {
    __shared__ float tile[32][33];
    int n0 = blockIdx.x * 32, k0 = blockIdx.y * 32;
    int tx = threadIdx.x, ty = threadIdx.y;   // block (32,8)
#pragma unroll
    for (int i = 0; i < 4; ++i)
        tile[ty + 8 * i][tx] = in[(size_t)(k0 + ty + 8 * i) * N + n0 + tx];
    __syncthreads();
#pragma unroll
    for (int i = 0; i < 4; ++i)
        out[(size_t)(n0 + ty + 8 * i) * K + k0 + tx] = (__bf16)tile[tx][ty + 8 * i];
}

// ---------------- GEMM: C[M][N] = A[M][K] @ Bt[N][K]^T + bias ----------------
// A, Bt bf16 (K contiguous). 128x128 tile, BK=32, 256 threads (4 waves, each 64x64).
template <bool OUT_BF16>
__global__ __launch_bounds__(256) void gemm_bt(const __bf16* __restrict__ A,
                                               const __bf16* __restrict__ Bt,
                                               const float* __restrict__ bias,
                                               void* __restrict__ Cout,
                                               int M, int N, int K) {
    __shared__ __bf16 As[128 * 32];
    __shared__ __bf16 Bs[128 * 32];
    const int tid  = threadIdx.x;
    const int wave = tid >> 6;
    const int lane = tid & 63;
    const int lrow = lane & 15;
    const int quad = lane >> 4;
    const int wm   = (wave >> 1) * 64;
    const int wn   = (wave & 1) * 64;
    const int tm   = blockIdx.x * 128;
    const int tn   = blockIdx.y * 128;

    f32x4 acc[4][4] = {};

    const int srow = lane >> 2;        // 0..15 within chunk
    const int skoff = (lane & 3) * 8;  // element offset within BK row

    for (int k0 = 0; k0 < K; k0 += 32) {
        __syncthreads();
#pragma unroll
        for (int i = 0; i < 2; ++i) {
            int c = wave * 2 + i;                    // chunk 0..7 => rows 16c..16c+15
            int row = 16 * c + srow;
            load_lds16(A + (size_t)(tm + row) * K + k0 + skoff, As + c * 512);
            load_lds16(Bt + (size_t)(tn + row) * K + k0 + skoff, Bs + c * 512);
        }
        __syncthreads();

        bf16x8 bfr[4];
#pragma unroll
        for (int ni = 0; ni < 4; ++ni)
            bfr[ni] = *(const bf16x8*)(Bs + (wn + ni * 16 + lrow) * 32 + quad * 8);
#pragma unroll
        for (int mi = 0; mi < 4; ++mi) {
            bf16x8 a = *(const bf16x8*)(As + (wm + mi * 16 + lrow) * 32 + quad * 8);
#pragma unroll
            for (int ni = 0; ni < 4; ++ni)
                acc[mi][ni] = mfma16(a, bfr[ni], acc[mi][ni]);
        }
    }

    // epilogue: C row = quad*4+r, col = lrow (per 16x16 tile)
#pragma unroll
    for (int ni = 0; ni < 4; ++ni) {
        int cn = tn + wn + ni * 16 + lrow;
        float bv = bias[cn];
#pragma unroll
        for (int mi = 0; mi < 4; ++mi) {
#pragma unroll
            for (int r = 0; r < 4; ++r) {
                int gm = tm + wm + mi * 16 + quad * 4 + r;
                float v = acc[mi][ni][r] + bv;
                if (OUT_BF16)
                    ((__bf16*)Cout)[(size_t)gm * N + cn] = (__bf16)v;
                else
                    ((float*)Cout)[(size_t)gm * N + cn] = v;
            }
        }
    }
}

// ---------------- Flash attention ----------------
// qkv: [B*S][3E] bf16 (q at col h*64, k at 1024+h*64, v at 2048+h*64)
// y:   [B*S][E]  bf16 (col h*64+d)
// grid (S/64, H, B), block 256 (4 waves; wave w owns q rows qbase+16w..+15)
#define VT_LD 80   // padded key-stride for Vt rows (d-major)
#define P_LD 80    // padded key-stride for P rows
__global__ __launch_bounds__(256) void attn(const __bf16* __restrict__ qkv,
                                            __bf16* __restrict__ y) {
    const int qt = blockIdx.x, h = blockIdx.y, b = blockIdx.z;
    const int tid = threadIdx.x;
    const int wave = tid >> 6, lane = tid & 63;
    const int lrow = lane & 15, quad = lane >> 4;
    const int qbase = qt * 64;
    const size_t rs = QKV_N;
    const __bf16* qkv_b = qkv + (size_t)b * SS * rs;

    __shared__ __bf16 Vt[DD * VT_LD];          // Vt[d][key], 64 keys per block
    __shared__ __bf16 Plds[4 * 16 * P_LD];     // per-wave P tile [16 q][64 key]
    __bf16* pw = Plds + wave * 16 * P_LD;

    // Q fragments (A-operand layout): lane -> Q[qbase+16w+lrow][quad*8+j]
    const int qrow = qbase + wave * 16 + lrow;
    bf16x8 qf0, qf1;
    {
        const __bf16* qp = qkv_b + (size_t)qrow * rs + h * 64 + quad * 8;
        qf0 = *(const bf16x8*)qp;
        qf1 = *(const bf16x8*)(qp + 32);
    }

    float m_prev[4], l_sum[4];
#pragma unroll
    for (int r = 0; r < 4; ++r) { m_prev[r] = -INFINITY; l_sum[r] = 0.f; }
    f32x4 oacc[4] = {};   // d-tiles t=0..3; reg r -> q row quad*4+r, col d=t*16+lrow

    const int nkb = qt + 1;
    for (int kb_i = 0; kb_i < nkb; ++kb_i) {
        const int kb = kb_i * 64;
        __syncthreads();
        // stage V^T: Vt[d][key] <- V[kb+key][d]
#pragma unroll
        for (int rep = 0; rep < 2; ++rep) {
            int idx = tid + rep * 256;           // 512 chunks of 8 d
            int key = idx >> 3;
            int dc = (idx & 7) * 8;
            bf16x8 v = *(const bf16x8*)(qkv_b + (size_t)(kb + key) * rs + 2048 + h * 64 + dc);
#pragma unroll
            for (int i = 0; i < 8; ++i) Vt[(dc + i) * VT_LD + key] = v[i];
        }
        __syncthreads();

        // QK^T: 4 key tiles of 16
        float p[4][4];
#pragma unroll
        for (int t = 0; t < 4; ++t) {
            const __bf16* kp = qkv_b + (size_t)(kb + t * 16 + lrow) * rs + 1024 + h * 64 + quad * 8;
            bf16x8 kf0 = *(const bf16x8*)kp;
            bf16x8 kf1 = *(const bf16x8*)(kp + 32);
            f32x4 s = {};
            s = mfma16(qf0, kf0, s);
            s = mfma16(qf1, kf1, s);
            int key = kb + t * 16 + lrow;
#pragma unroll
            for (int r = 0; r < 4; ++r) {
                int q = qbase + wave * 16 + quad * 4 + r;
                p[t][r] = (key <= q) ? s[r] * 0.125f : -INFINITY;
            }
        }

        // online softmax per q row (rows live on 16 lanes sharing a quad)
#pragma unroll
        for (int r = 0; r < 4; ++r) {
            float mx = fmaxf(fmaxf(p[0][r], p[1][r]), fmaxf(p[2][r], p[3][r]));
#pragma unroll
            for (int off = 1; off < 16; off <<= 1) mx = fmaxf(mx, __shfl_xor(mx, off, 64));
            float mnew = fmaxf(m_prev[r], mx);
            float alpha = __expf(m_prev[r] - mnew);
            float sum = 0.f;
#pragma unroll
            for (int t = 0; t < 4; ++t) { float e = __expf(p[t][r] - mnew); p[t][r] = e; sum += e; }
#pragma unroll
            for (int off = 1; off < 16; off <<= 1) sum += __shfl_xor(sum, off, 64);
            l_sum[r] = l_sum[r] * alpha + sum;
            m_prev[r] = mnew;
#pragma unroll
            for (int t = 0; t < 4; ++t) oacc[t][r] *= alpha;
        }

        // P (C-layout) -> LDS (row-major [q][key]) for A-operand reads
#pragma unroll
        for (int t = 0; t < 4; ++t)
#pragma unroll
            for (int r = 0; r < 4; ++r)
                pw[(quad * 4 + r) * P_LD + t * 16 + lrow] = (__bf16)p[t][r];
        // wave-private LDS region: compiler-inserted lgkmcnt wait suffices (no barrier)

        // PV: O[q][d] += P[q][key] V[key][d], key in 2 halves of 32
#pragma unroll
        for (int kh = 0; kh < 2; ++kh) {
            bf16x8 af = *(const bf16x8*)(pw + lrow * P_LD + kh * 32 + quad * 8);
#pragma unroll
            for (int t = 0; t < 4; ++t) {
                bf16x8 vf = *(const bf16x8*)(Vt + (t * 16 + lrow) * VT_LD + kh * 32 + quad * 8);
                oacc[t] = mfma16(af, vf, oacc[t]);
            }
        }
    }

    // epilogue: y[b*S+q][h*64 + t*16 + lrow] = O / l
#pragma unroll
    for (int t = 0; t < 4; ++t) {
#pragma unroll
        for (int r = 0; r < 4; ++r) {
            int q = qbase + wave * 16 + quad * 4 + r;
            float v = oacc[t][r] / l_sum[r];
            y[(size_t)(b * SS + q) * EE + h * 64 + t * 16 + lrow] = (__bf16)v;
        }
    }
}

// ---------------- launch ----------------
extern "C" void kernel_launch(void* const* d_in, const int* in_sizes, int n_in,
                              void* d_out, int out_size, void* d_ws, size_t ws_size,
                              hipStream_t stream) {
    const float* x      = (const float*)d_in[0];
    const float* w_qkv  = (const float*)d_in[1];
    const float* b_qkv  = (const float*)d_in[2];
    const float* w_proj = (const float*)d_in[3];
    const float* b_proj = (const float*)d_in[4];
    float* out = (float*)d_out;

    __bf16* xb     = (__bf16*)d_ws;
    __bf16* wqkvT  = xb + (size_t)ROWS * EE;            // [3072][1024]
    __bf16* wprojT = wqkvT + (size_t)QKV_N * EE;        // [1024][1024]
    __bf16* qkv    = wprojT + (size_t)EE * EE;          // [8192][3072]
    __bf16* yb     = qkv + (size_t)ROWS * QKV_N;        // [8192][1024]

    // 1. cast x -> bf16 (8192*1024 elems, 4/thread)
    cast_f32_bf16<<<dim3(ROWS * EE / 1024), dim3(256), 0, stream>>>(x, xb);
    // 2. w_qkv [1024][3072] -> [3072][1024] bf16
    transpose_cast<<<dim3(QKV_N / 32, EE / 32), dim3(32, 8), 0, stream>>>(w_qkv, wqkvT, EE, QKV_N);
    // 3. w_proj [1024][1024] -> [1024][1024] bf16 (transposed)
    transpose_cast<<<dim3(EE / 32, EE / 32), dim3(32, 8), 0, stream>>>(w_proj, wprojT, EE, EE);
    // 4. qkv = xb @ wqkvT^T + b_qkv  (bf16 out)
    gemm_bt<true><<<dim3(ROWS / 128, QKV_N / 128), dim3(256), 0, stream>>>(
        xb, wqkvT, b_qkv, (void*)qkv, ROWS, QKV_N, EE);
    // 5. attention
    attn<<<dim3(SS / 64, HH, BB), dim3(256), 0, stream>>>(qkv, yb);
    // 6. out = yb @ wprojT^T + b_proj (fp32 out)
    gemm_bt<false><<<dim3(ROWS / 128, EE / 128), dim3(256), 0, stream>>>(
        yb, wprojT, b_proj, (void*)out, ROWS, EE, EE);
}

// Round 2
// 366.035 us; speedup vs baseline: 1.4395x; 1.4395x over previous
//
#include <hip/hip_runtime.h>
#include <cmath>
#include <cstdint>

// Shapes (fixed for this problem)
#define BB 4
#define SS 2048
#define EE 1024
#define HH 16
#define DD 64
#define ROWS (BB*SS)          // 8192
#define QKV_N (3*EE)          // 3072

using bf16x8 = __attribute__((ext_vector_type(8))) __bf16;
using bf16x4 = __attribute__((ext_vector_type(4))) __bf16;
using f32x4  = __attribute__((ext_vector_type(4))) float;

__device__ inline f32x4 mfma16(bf16x8 a, bf16x8 b, f32x4 c) {
    return __builtin_amdgcn_mfma_f32_16x16x32_bf16(a, b, c, 0, 0, 0);
}

__device__ inline void load_lds16(const void* g, void* l) {
    __builtin_amdgcn_global_load_lds(
        (__attribute__((address_space(1))) void*)g,
        (__attribute__((address_space(3))) void*)l, 16, 0, 0);
}

// ---------------- cast fp32 -> bf16, vectorized ----------------
__global__ __launch_bounds__(256) void cast_f32_bf16(const float* __restrict__ in,
                                                     __bf16* __restrict__ out) {
    size_t i = ((size_t)blockIdx.x * 256 + threadIdx.x) * 4;
    float4 v = *(const float4*)(in + i);
    bf16x4 o;
    o[0] = (__bf16)v.x; o[1] = (__bf16)v.y; o[2] = (__bf16)v.z; o[3] = (__bf16)v.w;
    *(bf16x4*)(out + i) = o;
}

// ---------------- transpose + cast: in [K][N] f32 -> out [N][K] bf16 ----------------
__global__ __launch_bounds__(256) void transpose_cast(const float* __restrict__ in,
                                                      __bf16* __restrict__ out,
                                                      int K, int N) {
    __shared__ float tile[32][33];
    int n0 = blockIdx.x * 32, k0 = blockIdx.y * 32;
    int tx = threadIdx.x, ty = threadIdx.y;   // block (32,8)
#pragma unroll
    for (int i = 0; i < 4; ++i)
        tile[ty + 8 * i][tx] = in[(size_t)(k0 + ty + 8 * i) * N + n0 + tx];
    __syncthreads();
#pragma unroll
    for (int i = 0; i < 4; ++i)
        out[(size_t)(n0 + ty + 8 * i) * K + k0 + tx] = (__bf16)tile[tx][ty + 8 * i];
}

// ---------------- V transpose: qkv V-section -> vt[b][h][d][s] bf16 ----------------
// grid (S/64, H, B), block 256
__global__ __launch_bounds__(256) void build_vt(const __bf16* __restrict__ qkv,
                                                __bf16* __restrict__ vt) {
    __shared__ __bf16 tile[64 * 72];   // [s][d] padded
    const int s0 = blockIdx.x * 64, h = blockIdx.y, b = blockIdx.z;
    const int tid = threadIdx.x;
#pragma unroll
    for (int r = 0; r < 2; ++r) {
        int c = r * 256 + tid;                 // 0..511
        int s = c >> 3, dp = c & 7;
        bf16x8 v = *(const bf16x8*)(qkv + (size_t)(b * SS + s0 + s) * QKV_N + 2048 + h * 64 + dp * 8);
        *(bf16x8*)(tile + s * 72 + dp * 8) = v;
    }
    __syncthreads();
#pragma unroll
    for (int r = 0; r < 2; ++r) {
        int c = r * 256 + tid;
        int d = c >> 3, sp = c & 7;
        bf16x8 o;
#pragma unroll
        for (int i = 0; i < 8; ++i) o[i] = tile[(sp * 8 + i) * 72 + d];
        *(bf16x8*)(vt + (size_t)((b * HH + h) * 64 + d) * SS + s0 + sp * 8) = o;
    }
}

// ---------------- GEMM: C[M][N] = A[M][K] @ Bt[N][K]^T + bias ----------------
template <bool OUT_BF16>
__global__ __launch_bounds__(256) void gemm_bt(const __bf16* __restrict__ A,
                                               const __bf16* __restrict__ Bt,
                                               const float* __restrict__ bias,
                                               void* __restrict__ Cout,
                                               int M, int N, int K) {
    __shared__ __bf16 As[128 * 32];
    __shared__ __bf16 Bs[128 * 32];
    const int tid  = threadIdx.x;
    const int wave = tid >> 6;
    const int lane = tid & 63;
    const int lrow = lane & 15;
    const int quad = lane >> 4;
    const int wm   = (wave >> 1) * 64;
    const int wn   = (wave & 1) * 64;
    const int tm   = blockIdx.x * 128;
    const int tn   = blockIdx.y * 128;

    f32x4 acc[4][4] = {};

    const int srow = lane >> 2;
    const int skoff = (lane & 3) * 8;

    for (int k0 = 0; k0 < K; k0 += 32) {
        __syncthreads();
#pragma unroll
        for (int i = 0; i < 2; ++i) {
            int c = wave * 2 + i;
            int row = 16 * c + srow;
            load_lds16(A + (size_t)(tm + row) * K + k0 + skoff, As + c * 512);
            load_lds16(Bt + (size_t)(tn + row) * K + k0 + skoff, Bs + c * 512);
        }
        __syncthreads();

        bf16x8 bfr[4];
#pragma unroll
        for (int ni = 0; ni < 4; ++ni)
            bfr[ni] = *(const bf16x8*)(Bs + (wn + ni * 16 + lrow) * 32 + quad * 8);
#pragma unroll
        for (int mi = 0; mi < 4; ++mi) {
            bf16x8 a = *(const bf16x8*)(As + (wm + mi * 16 + lrow) * 32 + quad * 8);
#pragma unroll
            for (int ni = 0; ni < 4; ++ni)
                acc[mi][ni] = mfma16(a, bfr[ni], acc[mi][ni]);
        }
    }

#pragma unroll
    for (int ni = 0; ni < 4; ++ni) {
        int cn = tn + wn + ni * 16 + lrow;
        float bv = bias[cn];
#pragma unroll
        for (int mi = 0; mi < 4; ++mi) {
#pragma unroll
            for (int r = 0; r < 4; ++r) {
                int gm = tm + wm + mi * 16 + quad * 4 + r;
                float v = acc[mi][ni][r] + bv;
                if (OUT_BF16)
                    ((__bf16*)Cout)[(size_t)gm * N + cn] = (__bf16)v;
                else
                    ((float*)Cout)[(size_t)gm * N + cn] = v;
            }
        }
    }
}

// ---------------- Flash attention v2 (S^T / O^T formulation) ----------------
// qkv: [B*S][3E] bf16 ; vt: [B][H][64 d][2048 s] bf16 ; y: [B*S][E] bf16
// grid (S/64, H, B) with qt reversed (heavy blocks first), block 256.
// LDS tiles staged via global_load_lds with XOR-swizzled gather addresses:
//   Klds[key][d-chunk8 ^ (key&7)]  -> b128 A-frag reads conflict-free
//   Vlds[d][s-chunk8 ^ (d&7)]      -> b128 A-frag reads conflict-free
__global__ __launch_bounds__(256) void attn2(const __bf16* __restrict__ qkv,
                                             const __bf16* __restrict__ vt,
                                             __bf16* __restrict__ y) {
    const int qt = gridDim.x - 1 - blockIdx.x;
    const int h = blockIdx.y, b = blockIdx.z;
    const int tid = threadIdx.x;
    const int wave = tid >> 6, lane = tid & 63;
    const int lrow = lane & 15, quad = lane >> 4;
    const int qbase = qt * 64;

    __shared__ __bf16 Klds[64 * 64];      // 8 KB
    __shared__ __bf16 Vlds[64 * 64];      // 8 KB
    __shared__ __bf16 Plds[4 * 16 * 72];  // 9 KB, per-wave [16 q][72 key-pad]
    __bf16* Pw = Plds + wave * 16 * 72;

    // this lane's q row (S^T column): q = qbase + 16*wave + lrow
    const int qg = qbase + wave * 16 + lrow;
    const __bf16* qp = qkv + (size_t)(b * SS + qg) * QKV_N + h * 64;
    bf16x8 qf0 = *(const bf16x8*)(qp + quad * 8);        // B-frag: Q[q=lrow][d=quad*8+j]
    bf16x8 qf1 = *(const bf16x8*)(qp + 32 + quad * 8);

    float m2 = -INFINITY, l = 0.f;
    f32x4 oacc[4] = {};   // O^T tile td: reg r -> d = 16*td + 4*quad + r, col q = lrow

    const int nkb = qt + 1;
    for (int kb_i = 0; kb_i < nkb; ++kb_i) {
        const int kb = kb_i * 64;
        __syncthreads();   // prior iter's LDS reads complete
#pragma unroll
        for (int r = 0; r < 2; ++r) {
            int c = r * 256 + tid;                    // chunk 0..511 (16B each)
            int row = c >> 3;
            int gg = (c & 7) ^ (row & 7);             // swizzled source chunk
            load_lds16(qkv + (size_t)(b * SS + kb + row) * QKV_N + 1024 + h * 64 + gg * 8,
                       Klds + c * 8);
            load_lds16(vt + (size_t)((b * HH + h) * 64 + row) * SS + kb + gg * 8,
                       Vlds + c * 8);
        }
        __syncthreads();

        // QK^T -> S^T: A = K[key=16t+lrow][d], B = Q. C[r]: key=kb+16t+4*quad+r, q=lrow
        f32x4 s[4];
#pragma unroll
        for (int t = 0; t < 4; ++t) {
            const __bf16* kr = Klds + (16 * t + lrow) * 64;
            bf16x8 kf0 = *(const bf16x8*)(kr + 8 * (quad ^ (lrow & 7)));
            bf16x8 kf1 = *(const bf16x8*)(kr + 8 * ((4 + quad) ^ (lrow & 7)));
            f32x4 a = {};
            a = mfma16(kf0, qf0, a);
            a = mfma16(kf1, qf1, a);
            s[t] = a;
        }

        const float sc = 0.18033688f;   // log2(e) / sqrt(64): softmax in base-2 domain
        float mx = -INFINITY;
        if (kb_i == nkb - 1) {          // only the diagonal block needs masking
#pragma unroll
            for (int t = 0; t < 4; ++t)
#pragma unroll
                for (int r = 0; r < 4; ++r) {
                    int key = kb + 16 * t + 4 * quad + r;
                    float v = (key <= qg) ? s[t][r] * sc : -INFINITY;
                    s[t][r] = v;
                    mx = fmaxf(mx, v);
                }
        } else {
#pragma unroll
            for (int t = 0; t < 4; ++t)
#pragma unroll
                for (int r = 0; r < 4; ++r) {
                    float v = s[t][r] * sc;
                    s[t][r] = v;
                    mx = fmaxf(mx, v);
                }
        }
        // stats per q=lrow: combine the 4 quads (2 shuffles)
        mx = fmaxf(mx, __shfl_xor(mx, 16));
        mx = fmaxf(mx, __shfl_xor(mx, 32));
        float mnew = fmaxf(m2, mx);
        float alpha = exp2f(m2 - mnew);
        m2 = mnew;
        float rs = 0.f;
#pragma unroll
        for (int t = 0; t < 4; ++t) {
            bf16x4 pk;
#pragma unroll
            for (int r = 0; r < 4; ++r) {
                float e = exp2f(s[t][r] - mnew);
                rs += e;
                pk[r] = (__bf16)e;
            }
            // store P row-major [q=lrow][key=16t+4*quad+r]: packed b64, ~2-way banks
            *(bf16x4*)(Pw + lrow * 72 + 16 * t + 4 * quad) = pk;
        }
        rs += __shfl_xor(rs, 16);
        rs += __shfl_xor(rs, 32);
        l = l * alpha + rs;
#pragma unroll
        for (int td = 0; td < 4; ++td) {
            oacc[td][0] *= alpha; oacc[td][1] *= alpha;
            oacc[td][2] *= alpha; oacc[td][3] *= alpha;
        }

        // O^T += V^T P^T: A = Vt[d=16td+lrow][key], B = P^T (read from P row q=lrow)
#pragma unroll
        for (int kh = 0; kh < 2; ++kh) {
            bf16x8 pf = *(const bf16x8*)(Pw + lrow * 72 + 32 * kh + 8 * quad);
#pragma unroll
            for (int td = 0; td < 4; ++td) {
                bf16x8 vf = *(const bf16x8*)(Vlds + (16 * td + lrow) * 64 +
                                             8 * ((4 * kh + quad) ^ (lrow & 7)));
                oacc[td] = mfma16(vf, pf, oacc[td]);
            }
        }
    }

    // epilogue: y[q=qg][h*64 + d], d = 16*td + 4*quad + r; packed 8B stores
    float linv = 1.f / l;
    __bf16* yp = y + (size_t)(b * SS + qg) * EE + h * 64;
#pragma unroll
    for (int td = 0; td < 4; ++td) {
        bf16x4 o;
#pragma unroll
        for (int r = 0; r < 4; ++r) o[r] = (__bf16)(oacc[td][r] * linv);
        *(bf16x4*)(yp + 16 * td + 4 * quad) = o;
    }
}

// ---------------- launch ----------------
extern "C" void kernel_launch(void* const* d_in, const int* in_sizes, int n_in,
                              void* d_out, int out_size, void* d_ws, size_t ws_size,
                              hipStream_t stream) {
    const float* x      = (const float*)d_in[0];
    const float* w_qkv  = (const float*)d_in[1];
    const float* b_qkv  = (const float*)d_in[2];
    const float* w_proj = (const float*)d_in[3];
    const float* b_proj = (const float*)d_in[4];
    float* out = (float*)d_out;

    __bf16* xb     = (__bf16*)d_ws;                      // 16 MB (reused as vt later)
    __bf16* wqkvT  = xb + (size_t)ROWS * EE;             // [3072][1024]
    __bf16* wprojT = wqkvT + (size_t)QKV_N * EE;         // [1024][1024]
    __bf16* qkv    = wprojT + (size_t)EE * EE;           // [8192][3072]
    __bf16* yb     = qkv + (size_t)ROWS * QKV_N;         // [8192][1024]
    __bf16* vtb    = xb;                                 // alias: xb dead after GEMM1

    cast_f32_bf16<<<dim3(ROWS * EE / 1024), dim3(256), 0, stream>>>(x, xb);
    transpose_cast<<<dim3(QKV_N / 32, EE / 32), dim3(32, 8), 0, stream>>>(w_qkv, wqkvT, EE, QKV_N);
    transpose_cast<<<dim3(EE / 32, EE / 32), dim3(32, 8), 0, stream>>>(w_proj, wprojT, EE, EE);
    gemm_bt<true><<<dim3(ROWS / 128, QKV_N / 128), dim3(256), 0, stream>>>(
        xb, wqkvT, b_qkv, (void*)qkv, ROWS, QKV_N, EE);
    build_vt<<<dim3(SS / 64, HH, BB), dim3(256), 0, stream>>>(qkv, vtb);
    attn2<<<dim3(SS / 64, HH, BB), dim3(256), 0, stream>>>(qkv, vtb, yb);
    gemm_bt<false><<<dim3(ROWS / 128, EE / 128), dim3(256), 0, stream>>>(
        yb, wprojT, b_proj, (void*)out, ROWS, EE, EE);
}